// Round 9
// baseline (106.336 us; speedup 1.0000x reference)
//
#include <hip/hip_runtime.h>

#define NB 4
#define NQ 256
#define NK 1024
#define ND 512
#define NH 128

typedef _Float16 half8_t __attribute__((ext_vector_type(8)));
typedef _Float16 half4_t __attribute__((ext_vector_type(4)));
typedef float f32x4_t __attribute__((ext_vector_type(4)));

#define TANH_C 2.8853900817779268f  // 2*log2(e): tanh(x)=1-2/(exp2(C*x)+1)

// ---------------------------------------------------------------------------
// Kernel 1 (prep): blocks 0..15  : W (512,128) fp32 -> WT (128,512) fp16
//                  blocks 16..527: values (B,K,D) fp32 -> vT (B,D,K) fp16,
//                                  and zero a 4KB slice of d_out each.
// FIXED vs R6/R7: out-zero slice is out4[vb*256 + t] (2MB total, exactly
// out_size). Previous code wrote vb*1024+t+i*256 -> 8MB, 4x OOB on d_out
// -> memory-fault abort. That was the crash, not LDS.
// ---------------------------------------------------------------------------
__global__ __launch_bounds__(256) void prep_kernel(
    const float* __restrict__ Wq, const float* __restrict__ Wk,
    const float* __restrict__ values, _Float16* __restrict__ WQT,
    _Float16* __restrict__ WKT, _Float16* __restrict__ vT,
    float4* __restrict__ out4) {
  __shared__ float smem[64 * 130];
  const int bid = blockIdx.x;
  const int t = threadIdx.x;

  if (bid < 16) {  // ---- weight transpose: 64-d chunk of Wq or Wk ----
    float(*tile)[129] = (float(*)[129])smem;
    const float* W = (bid >= 8) ? Wk : Wq;
    _Float16* WT = (bid >= 8) ? WKT : WQT;
    const int d0 = (bid & 7) * 64;
    #pragma unroll
    for (int j = 0; j < 32; ++j) {
      const int idx = t + j * 256;
      tile[idx >> 7][idx & 127] = W[(size_t)(d0 + (idx >> 7)) * NH + (idx & 127)];
    }
    __syncthreads();
    #pragma unroll
    for (int j = 0; j < 32; ++j) {
      const int idx = t + j * 256;
      const int h = idx >> 6, r = idx & 63;
      WT[(size_t)h * ND + d0 + r] = (_Float16)tile[r][h];
    }
    return;
  }

  // ---- values transpose (64x64 tile) + zero 4KB of out ----
  const int vb = bid - 16;  // 0..511
  out4[(size_t)vb * 256 + t] = make_float4(0.f, 0.f, 0.f, 0.f);

  float(*tile)[65] = (float(*)[65])smem;
  const int dt = vb & 7;
  const int kt = (vb >> 3) & 15;
  const int b = vb >> 7;
  const int k0 = kt * 64, d0 = dt * 64;
  {
    const int kl = t >> 4, dl4 = (t & 15) * 4;
    #pragma unroll
    for (int i = 0; i < 4; ++i) {
      const float4 v = *(const float4*)(
          values + ((size_t)(b * NK + k0 + kl + i * 16)) * ND + d0 + dl4);
      tile[dl4 + 0][kl + i * 16] = v.x;
      tile[dl4 + 1][kl + i * 16] = v.y;
      tile[dl4 + 2][kl + i * 16] = v.z;
      tile[dl4 + 3][kl + i * 16] = v.w;
    }
  }
  __syncthreads();
  const int dr = t >> 2, kc = (t & 3) * 16;
  half8_t h0, h1;
  #pragma unroll
  for (int ii = 0; ii < 8; ++ii) {
    h0[ii] = (_Float16)tile[dr][kc + ii];
    h1[ii] = (_Float16)tile[dr][kc + 8 + ii];
  }
  _Float16* dst = vT + ((size_t)(b * ND + d0 + dr)) * NK + k0 + kc;
  *(half8_t*)dst = h0;
  *(half8_t*)(dst + 8) = h1;
}

// ---------------------------------------------------------------------------
// Kernel 2: projection via MFMA fp16 + exp2 epilogue.
// Rows 0..1023 = queries->EQ, 1024..5119 = keys->EK. Block = 16 rows, 4
// waves; wave w owns h = w*32..w*32+31 (2 n-frags). K-dim = 512.
// ---------------------------------------------------------------------------
__global__ __launch_bounds__(256) void proj_mfma_kernel(
    const float* __restrict__ queries, const float* __restrict__ keys,
    const _Float16* __restrict__ WQT, const _Float16* __restrict__ WKT,
    float* __restrict__ EQ, float* __restrict__ EK) {
  const int bid = blockIdx.x;
  const int row0 = bid * 16;
  const bool is_q = row0 < NB * NQ;
  const float* X = is_q ? queries : (keys - (size_t)NB * NQ * ND);
  const _Float16* WT = is_q ? WQT : WKT;
  float* Y = is_q ? EQ : (EK - (size_t)NB * NQ * NH);

  const int w = threadIdx.x >> 6;
  const int l = threadIdx.x & 63;
  const int h0 = w * 32;

  const float* xrow = X + (size_t)(row0 + (l & 15)) * ND + (l >> 4) * 8;
  const _Float16* wt0 = WT + (size_t)(h0 + (l & 15)) * ND + (l >> 4) * 8;
  const _Float16* wt1 = wt0 + 16 * ND;

  f32x4_t acc0 = {0.f, 0.f, 0.f, 0.f};
  f32x4_t acc1 = {0.f, 0.f, 0.f, 0.f};
  #pragma unroll 4
  for (int d = 0; d < ND; d += 32) {
    const float4 x0 = *(const float4*)(xrow + d);
    const float4 x1 = *(const float4*)(xrow + d + 4);
    half8_t a;
    a[0] = (_Float16)x0.x; a[1] = (_Float16)x0.y;
    a[2] = (_Float16)x0.z; a[3] = (_Float16)x0.w;
    a[4] = (_Float16)x1.x; a[5] = (_Float16)x1.y;
    a[6] = (_Float16)x1.z; a[7] = (_Float16)x1.w;
    const half8_t b0 = *(const half8_t*)(wt0 + d);
    const half8_t b1 = *(const half8_t*)(wt1 + d);
    acc0 = __builtin_amdgcn_mfma_f32_16x16x32_f16(a, b0, acc0, 0, 0, 0);
    acc1 = __builtin_amdgcn_mfma_f32_16x16x32_f16(a, b1, acc1, 0, 0, 0);
  }
  const int mrow = row0 + (l >> 4) * 4;
  const int hcol = h0 + (l & 15);
  #pragma unroll
  for (int r = 0; r < 4; ++r) {
    Y[(size_t)(mrow + r) * NH + hcol] = __builtin_exp2f(TANH_C * acc0[r]);
    Y[(size_t)(mrow + r) * NH + hcol + 16] = __builtin_exp2f(TANH_C * acc1[r]);
  }
}

// ---------------------------------------------------------------------------
// Kernel 3: fused scores + softmax -> fp16 attn. Block = (b, 4 q-rows),
// grid 256, wave = q-row, lane = k-within-chunk. 16 chunks of 64 k; scores
// live in 16 VGPRs/lane. One chunk staged per barrier pair (32 KB LDS,
// XOR-swizzled float4: idx = row*32 + (slot^(row&7)) -- proven R5 layout).
// Per-float4 math pairs reciprocals: w1/d1+w2/d2 = (w1*d2+w2*d1)*rcp(d1*d2).
// Masked logits -> 0, kept in softmax (ref semantics).
// ---------------------------------------------------------------------------
__global__ __launch_bounds__(256) void scores_softmax_kernel(
    const float* __restrict__ EQ, const float* __restrict__ EK,
    const float* __restrict__ wv, const int* __restrict__ vlen,
    _Float16* __restrict__ attn_h) {
  __shared__ float khs[64 * NH];  // 32 KB
  __shared__ float eqs[4][NH];
  __shared__ float wvs[NH];
  const int bid = blockIdx.x;
  const int qt = bid & 63;
  const int b = bid >> 6;
  const int q0 = qt * 4;
  const int t = threadIdx.x;
  const int myq = t >> 6;
  const int l = t & 63;
  const int vl = vlen[b];

  if (t < 128) {
    const int r = t >> 5, c = t & 31;
    ((float4*)&eqs[r][0])[c] =
        ((const float4*)(EQ + (size_t)(b * NQ + q0 + r) * NH))[c];
  } else if (t < 160) {
    ((float4*)wvs)[t - 128] = ((const float4*)wv)[t - 128];
  }

  float sc[16];
  #pragma unroll
  for (int c = 0; c < 16; ++c) sc[c] = 0.f;

  float4* khs4 = (float4*)khs;
  const float4* eq4 = (const float4*)&eqs[myq][0];
  const float4* wv4 = (const float4*)wvs;

  for (int ch = 0; ch < 16; ++ch) {  // vl block-uniform: uniform control flow
    const int k0 = ch * 64;
    if (k0 >= vl) break;
    __syncthreads();
    {  // stage 64 k-rows x 128 floats coalesced, swizzled store (R5 layout)
      const float4* src = (const float4*)(EK + ((size_t)b * NK + k0) * NH);
      #pragma unroll
      for (int i = 0; i < 8; ++i) {
        const int idx = t + i * 256;
        const int row = idx >> 5, slot = idx & 31;
        khs4[row * 32 + (slot ^ (row & 7))] = src[idx];
      }
    }
    __syncthreads();
    float acc = 0.f;
    const int base = l * 32;
    const int lx = l & 7;
    #pragma unroll
    for (int slot = 0; slot < 32; ++slot) {
      const float4 e = khs4[base + (slot ^ lx)];
      const float4 q4 = eq4[slot];
      const float4 w4 = wv4[slot];
      const float dx = fmaf(q4.x, e.x, 1.f);
      const float dy = fmaf(q4.y, e.y, 1.f);
      const float dz = fmaf(q4.z, e.z, 1.f);
      const float dw = fmaf(q4.w, e.w, 1.f);
      const float n1 = fmaf(w4.x, dy, w4.y * dx);
      const float n2 = fmaf(w4.z, dw, w4.w * dz);
      acc = fmaf(n1, __builtin_amdgcn_rcpf(dx * dy), acc);
      acc = fmaf(n2, __builtin_amdgcn_rcpf(dz * dw), acc);
    }
    sc[ch] = acc;
  }

  // Wsum = sum_h wv[h]; finalize scores (masked -> 0, reference semantics)
  float Wsum = wvs[l] + wvs[l + 64];
  #pragma unroll
  for (int off = 32; off; off >>= 1) Wsum += __shfl_xor(Wsum, off);
  #pragma unroll
  for (int c = 0; c < 16; ++c) {
    const int k = c * 64 + l;
    sc[c] = (k < vl) ? (Wsum - 2.f * sc[c]) : 0.f;
  }

  // wave softmax over the 1024 values (zeros included, as in reference)
  float m = sc[0];
  #pragma unroll
  for (int c = 1; c < 16; ++c) m = fmaxf(m, sc[c]);
  #pragma unroll
  for (int off = 32; off; off >>= 1) m = fmaxf(m, __shfl_xor(m, off));
  const float ce = 1.4426950408889634f;
  float sum = 0.f;
  #pragma unroll
  for (int c = 0; c < 16; ++c) {
    sc[c] = __builtin_exp2f(ce * (sc[c] - m));
    sum += sc[c];
  }
  #pragma unroll
  for (int off = 32; off; off >>= 1) sum += __shfl_xor(sum, off);
  const float inv = 1.0f / sum;
  _Float16* orow = attn_h + (size_t)(b * NQ + q0 + myq) * NK;
  #pragma unroll
  for (int c = 0; c < 16; ++c) orow[c * 64 + l] = (_Float16)(sc[c] * inv);
}

// ---------------------------------------------------------------------------
// Kernel 4: PV via MFMA fp16, k-split by 4 (grid 1024, 4 blocks/CU).
// Partials atomicAdd'ed into out (zeroed by prep_kernel).
// ---------------------------------------------------------------------------
__global__ __launch_bounds__(256) void pv_mfma_kernel(
    const _Float16* __restrict__ attn_h, const _Float16* __restrict__ vT,
    float* __restrict__ out) {
  const int bid = blockIdx.x;
  const int kc  = bid & 3;
  const int nt8 = (bid >> 2) & 7;
  const int mt  = (bid >> 5) & 7;
  const int b   = bid >> 8;
  const int w = threadIdx.x >> 6;
  const int l = threadIdx.x & 63;
  const int mtile = w & 1;
  const int ntile0 = (w >> 1) * 2;
  const int q_lo = mt * 32 + mtile * 16;
  const int d_lo = nt8 * 64 + ntile0 * 16;
  const int k0 = kc * 256;

  const _Float16* arow =
      attn_h + ((size_t)(b * NQ + q_lo + (l & 15))) * NK + k0 + (l >> 4) * 8;
  const _Float16* brow0 =
      vT + ((size_t)(b * ND + d_lo + (l & 15))) * NK + k0 + (l >> 4) * 8;
  const _Float16* brow1 = brow0 + 16 * NK;

  f32x4_t acc0 = {0.f, 0.f, 0.f, 0.f};
  f32x4_t acc1 = {0.f, 0.f, 0.f, 0.f};
  #pragma unroll
  for (int ks = 0; ks < 256; ks += 32) {
    const half8_t a  = *(const half8_t*)(arow + ks);
    const half8_t b0 = *(const half8_t*)(brow0 + ks);
    const half8_t b1 = *(const half8_t*)(brow1 + ks);
    acc0 = __builtin_amdgcn_mfma_f32_16x16x32_f16(a, b0, acc0, 0, 0, 0);
    acc1 = __builtin_amdgcn_mfma_f32_16x16x32_f16(a, b1, acc1, 0, 0, 0);
  }
  const int mrow = q_lo + (l >> 4) * 4;
  const int dcol = d_lo + (l & 15);
  #pragma unroll
  for (int r = 0; r < 4; ++r) {
    atomicAdd(&out[(size_t)(b * NQ + mrow + r) * ND + dcol], acc0[r]);
    atomicAdd(&out[(size_t)(b * NQ + mrow + r) * ND + dcol + 16], acc1[r]);
  }
}

// ---------------------------------------------------------------------------
extern "C" void kernel_launch(void* const* d_in, const int* in_sizes, int n_in,
                              void* d_out, int out_size, void* d_ws, size_t ws_size,
                              hipStream_t stream) {
  const float* queries = (const float*)d_in[0];
  const float* keys    = (const float*)d_in[1];
  const float* values  = (const float*)d_in[2];
  const float* Wq      = (const float*)d_in[3];
  const float* Wk      = (const float*)d_in[4];
  const float* wv      = (const float*)d_in[5];
  const int*   vlen    = (const int*)d_in[6];
  float* out = (float*)d_out;

  // ws layout (bytes, no overlays; total ~8.96 MB; d_ws is ~256 MB):
  char* ws = (char*)d_ws;
  float*     EQ     = (float*)(ws);                    // 512 KB
  float*     EK     = (float*)(ws + (512 << 10));      // 2 MB
  _Float16*  attn_h = (_Float16*)(ws + (2560 << 10));  // 2 MB
  _Float16*  vT     = (_Float16*)(ws + (4608 << 10));  // 4 MB
  _Float16*  WQT    = (_Float16*)(ws + (8704 << 10));  // 128 KB
  _Float16*  WKT    = (_Float16*)(ws + (8832 << 10));  // 128 KB

  prep_kernel<<<528, 256, 0, stream>>>(Wq, Wk, values, WQT, WKT, vT,
                                       (float4*)out);
  proj_mfma_kernel<<<(NB * NQ + NB * NK) / 16, 256, 0, stream>>>(
      queries, keys, WQT, WKT, EQ, EK);
  scores_softmax_kernel<<<NB * 64, 256, 0, stream>>>(EQ, EK, wv, vlen, attn_h);
  pv_mfma_kernel<<<NB * 8 * 8 * 4, 256, 0, stream>>>(attn_h, vT, out);
}

// Round 10
// 59.231 us; speedup vs baseline: 1.7953x; 1.7953x over previous
//
#include <hip/hip_runtime.h>

#define NB 4
#define NQ 256
#define NK 1024
#define ND 512
#define NH 128

typedef _Float16 half8_t __attribute__((ext_vector_type(8)));
typedef _Float16 half4_t __attribute__((ext_vector_type(4)));
typedef float f32x4_t __attribute__((ext_vector_type(4)));

#define TANH_C 2.8853900817779268f  // 2*log2(e): tanh(x)=1-2/(exp2(C*x)+1)

// ---------------------------------------------------------------------------
// Kernel 1 (prep): blocks 0..15  : W (512,128) fp32 -> WT (128,512) fp16
//                  blocks 16..527: values (B,K,D) fp32 -> vT (B,D,K) fp16,
//                                  and zero a 4KB slice of d_out each.
// ---------------------------------------------------------------------------
__global__ __launch_bounds__(256) void prep_kernel(
    const float* __restrict__ Wq, const float* __restrict__ Wk,
    const float* __restrict__ values, _Float16* __restrict__ WQT,
    _Float16* __restrict__ WKT, _Float16* __restrict__ vT,
    float4* __restrict__ out4) {
  __shared__ float smem[64 * 130];
  const int bid = blockIdx.x;
  const int t = threadIdx.x;

  if (bid < 16) {  // ---- weight transpose: 64-d chunk of Wq or Wk ----
    float(*tile)[129] = (float(*)[129])smem;
    const float* W = (bid >= 8) ? Wk : Wq;
    _Float16* WT = (bid >= 8) ? WKT : WQT;
    const int d0 = (bid & 7) * 64;
    #pragma unroll
    for (int j = 0; j < 32; ++j) {
      const int idx = t + j * 256;
      tile[idx >> 7][idx & 127] = W[(size_t)(d0 + (idx >> 7)) * NH + (idx & 127)];
    }
    __syncthreads();
    #pragma unroll
    for (int j = 0; j < 32; ++j) {
      const int idx = t + j * 256;
      const int h = idx >> 6, r = idx & 63;
      WT[(size_t)h * ND + d0 + r] = (_Float16)tile[r][h];
    }
    return;
  }

  // ---- values transpose (64x64 tile) + zero 4KB of out ----
  const int vb = bid - 16;  // 0..511
  out4[(size_t)vb * 256 + t] = make_float4(0.f, 0.f, 0.f, 0.f);

  float(*tile)[65] = (float(*)[65])smem;
  const int dt = vb & 7;
  const int kt = (vb >> 3) & 15;
  const int b = vb >> 7;
  const int k0 = kt * 64, d0 = dt * 64;
  {
    const int kl = t >> 4, dl4 = (t & 15) * 4;
    #pragma unroll
    for (int i = 0; i < 4; ++i) {
      const float4 v = *(const float4*)(
          values + ((size_t)(b * NK + k0 + kl + i * 16)) * ND + d0 + dl4);
      tile[dl4 + 0][kl + i * 16] = v.x;
      tile[dl4 + 1][kl + i * 16] = v.y;
      tile[dl4 + 2][kl + i * 16] = v.z;
      tile[dl4 + 3][kl + i * 16] = v.w;
    }
  }
  __syncthreads();
  const int dr = t >> 2, kc = (t & 3) * 16;
  half8_t h0, h1;
  #pragma unroll
  for (int ii = 0; ii < 8; ++ii) {
    h0[ii] = (_Float16)tile[dr][kc + ii];
    h1[ii] = (_Float16)tile[dr][kc + 8 + ii];
  }
  _Float16* dst = vT + ((size_t)(b * ND + d0 + dr)) * NK + k0 + kc;
  *(half8_t*)dst = h0;
  *(half8_t*)(dst + 8) = h1;
}

// ---------------------------------------------------------------------------
// Kernel 2: projection via MFMA fp16 + exp2 epilogue.
// Rows 0..1023 = queries -> EQ[row][h] (row-major).
// Rows 1024..5119 = keys -> EKT[b][h][k] (TRANSPOSED, k contiguous): the
// D-fragment holds 4 consecutive m-rows (= k) at fixed col (= h), so the
// transposed store is a single float4 per fragment -- better coalesced than
// the 4 scalar row-major stores.
// ---------------------------------------------------------------------------
__global__ __launch_bounds__(256) void proj_mfma_kernel(
    const float* __restrict__ queries, const float* __restrict__ keys,
    const _Float16* __restrict__ WQT, const _Float16* __restrict__ WKT,
    float* __restrict__ EQ, float* __restrict__ EKT) {
  const int bid = blockIdx.x;
  const int row0 = bid * 16;
  const bool is_q = row0 < NB * NQ;
  const float* X = is_q ? queries : (keys - (size_t)NB * NQ * ND);
  const _Float16* WT = is_q ? WQT : WKT;

  const int w = threadIdx.x >> 6;
  const int l = threadIdx.x & 63;
  const int h0 = w * 32;

  const float* xrow = X + (size_t)(row0 + (l & 15)) * ND + (l >> 4) * 8;
  const _Float16* wt0 = WT + (size_t)(h0 + (l & 15)) * ND + (l >> 4) * 8;
  const _Float16* wt1 = wt0 + 16 * ND;

  f32x4_t acc0 = {0.f, 0.f, 0.f, 0.f};
  f32x4_t acc1 = {0.f, 0.f, 0.f, 0.f};
  #pragma unroll 4
  for (int d = 0; d < ND; d += 32) {
    const float4 x0 = *(const float4*)(xrow + d);
    const float4 x1 = *(const float4*)(xrow + d + 4);
    half8_t a;
    a[0] = (_Float16)x0.x; a[1] = (_Float16)x0.y;
    a[2] = (_Float16)x0.z; a[3] = (_Float16)x0.w;
    a[4] = (_Float16)x1.x; a[5] = (_Float16)x1.y;
    a[6] = (_Float16)x1.z; a[7] = (_Float16)x1.w;
    const half8_t b0 = *(const half8_t*)(wt0 + d);
    const half8_t b1 = *(const half8_t*)(wt1 + d);
    acc0 = __builtin_amdgcn_mfma_f32_16x16x32_f16(a, b0, acc0, 0, 0, 0);
    acc1 = __builtin_amdgcn_mfma_f32_16x16x32_f16(a, b1, acc1, 0, 0, 0);
  }
  const int mrow = row0 + (l >> 4) * 4;
  const int hcol = h0 + (l & 15);
  if (is_q) {
    #pragma unroll
    for (int r = 0; r < 4; ++r) {
      EQ[(size_t)(mrow + r) * NH + hcol] = __builtin_exp2f(TANH_C * acc0[r]);
      EQ[(size_t)(mrow + r) * NH + hcol + 16] = __builtin_exp2f(TANH_C * acc1[r]);
    }
  } else {
    const int rowk = mrow - NB * NQ;  // 0..4095
    const int bb = rowk >> 10;
    const int kk = rowk & 1023;       // multiple of 4 -> 16B aligned
    float4 v0, v1;
    v0.x = __builtin_exp2f(TANH_C * acc0[0]);
    v0.y = __builtin_exp2f(TANH_C * acc0[1]);
    v0.z = __builtin_exp2f(TANH_C * acc0[2]);
    v0.w = __builtin_exp2f(TANH_C * acc0[3]);
    v1.x = __builtin_exp2f(TANH_C * acc1[0]);
    v1.y = __builtin_exp2f(TANH_C * acc1[1]);
    v1.z = __builtin_exp2f(TANH_C * acc1[2]);
    v1.w = __builtin_exp2f(TANH_C * acc1[3]);
    *(float4*)(EKT + ((size_t)(bb * NH + hcol)) * NK + kk) = v0;
    *(float4*)(EKT + ((size_t)(bb * NH + hcol + 16)) * NK + kk) = v1;
  }
}

// ---------------------------------------------------------------------------
// Kernel 3: fused scores + softmax -> fp16 attn, NO LDS staging.
// Grid 512 = (b, q-pair); block 512 thr = 8 waves; wave = (myq = w&1,
// kc = w>>1); lane owns 4 k (k = kc*256 + l*4 + j). EKT reads are fully
// coalesced float4s along k (1KB/wave-instr); eq/wv pairs broadcast from a
// 2KB LDS table (float4 {eq_h, wv_h, eq_h+1, wv_h+1}). Occupancy: 2
// blocks/CU -> 4 waves/SIMD (R9's fused version had 1 -> latency-bound).
// Paired rcp across h: wa/da + wb/db = (wa*db + wb*da) * rcp(da*db).
// Masked logits -> 0 kept in softmax (reference semantics). Cross-wave
// softmax via 8-float LDS reduce.
// ---------------------------------------------------------------------------
__global__ __launch_bounds__(512, 4) void scores_softmax_kernel(
    const float* __restrict__ EQ, const float* __restrict__ EKT,
    const float* __restrict__ wv, const int* __restrict__ vlen,
    _Float16* __restrict__ attn_h) {
  __shared__ float4 eqwv2[2][64];  // [q][h/2] = {eq_h, wv_h, eq_h+1, wv_h+1}
  __shared__ float red[2][2][4];   // [pass][q][kc]
  const int bid = blockIdx.x;      // b*128 + qpair
  const int b = bid >> 7;
  const int q0 = (bid & 127) * 2;
  const int t = threadIdx.x;
  const int w = t >> 6;
  const int myq = w & 1;
  const int kc = w >> 1;
  const int l = t & 63;
  const int vl = vlen[b];

  if (t < 128) {
    const int qq = t >> 6, i = t & 63;
    const float* eqrow = EQ + (size_t)(b * NQ + q0 + qq) * NH;
    eqwv2[qq][i] = make_float4(eqrow[2 * i], wv[2 * i],
                               eqrow[2 * i + 1], wv[2 * i + 1]);
  }
  __syncthreads();

  // Wsum = sum_h wv[h] (redundant per wave, lane-parallel + shuffle)
  float Wsum;
  {
    const float4 a = eqwv2[0][l];
    Wsum = a.y + a.w;
    #pragma unroll
    for (int off = 32; off; off >>= 1) Wsum += __shfl_xor(Wsum, off);
  }

  const int k0 = kc * 256;
  float acc0 = 0.f, acc1 = 0.f, acc2 = 0.f, acc3 = 0.f;
  if (k0 < vl) {  // wave-uniform: skip fully-masked chunks
    const float* ekb = EKT + (size_t)(b * NH) * NK + k0 + l * 4;
    #pragma unroll 4
    for (int hh = 0; hh < 64; ++hh) {
      const float4 q4 = eqwv2[myq][hh];  // {eq_a, wv_a, eq_b, wv_b}
      const float4 ea = *(const float4*)(ekb + (size_t)(2 * hh) * NK);
      const float4 eb = *(const float4*)(ekb + (size_t)(2 * hh + 1) * NK);
      {
        const float da = fmaf(q4.x, ea.x, 1.f), db = fmaf(q4.z, eb.x, 1.f);
        acc0 = fmaf(fmaf(q4.y, db, q4.w * da),
                    __builtin_amdgcn_rcpf(da * db), acc0);
      }
      {
        const float da = fmaf(q4.x, ea.y, 1.f), db = fmaf(q4.z, eb.y, 1.f);
        acc1 = fmaf(fmaf(q4.y, db, q4.w * da),
                    __builtin_amdgcn_rcpf(da * db), acc1);
      }
      {
        const float da = fmaf(q4.x, ea.z, 1.f), db = fmaf(q4.z, eb.z, 1.f);
        acc2 = fmaf(fmaf(q4.y, db, q4.w * da),
                    __builtin_amdgcn_rcpf(da * db), acc2);
      }
      {
        const float da = fmaf(q4.x, ea.w, 1.f), db = fmaf(q4.z, eb.w, 1.f);
        acc3 = fmaf(fmaf(q4.y, db, q4.w * da),
                    __builtin_amdgcn_rcpf(da * db), acc3);
      }
    }
  }

  // finalize scores (masked -> 0, reference semantics)
  const int kbase = k0 + l * 4;
  float s0 = (kbase + 0 < vl) ? (Wsum - 2.f * acc0) : 0.f;
  float s1 = (kbase + 1 < vl) ? (Wsum - 2.f * acc1) : 0.f;
  float s2 = (kbase + 2 < vl) ? (Wsum - 2.f * acc2) : 0.f;
  float s3 = (kbase + 3 < vl) ? (Wsum - 2.f * acc3) : 0.f;

  // softmax over 1024 (4 kc-waves per q-row): wave reduce + LDS cross-wave
  float m = fmaxf(fmaxf(s0, s1), fmaxf(s2, s3));
  #pragma unroll
  for (int off = 32; off; off >>= 1) m = fmaxf(m, __shfl_xor(m, off));
  if (l == 0) red[0][myq][kc] = m;
  __syncthreads();
  m = fmaxf(fmaxf(red[0][myq][0], red[0][myq][1]),
            fmaxf(red[0][myq][2], red[0][myq][3]));
  const float ce = 1.4426950408889634f;
  s0 = __builtin_exp2f(ce * (s0 - m));
  s1 = __builtin_exp2f(ce * (s1 - m));
  s2 = __builtin_exp2f(ce * (s2 - m));
  s3 = __builtin_exp2f(ce * (s3 - m));
  float sum = s0 + s1 + s2 + s3;
  #pragma unroll
  for (int off = 32; off; off >>= 1) sum += __shfl_xor(sum, off);
  if (l == 0) red[1][myq][kc] = sum;
  __syncthreads();
  const float Z =
      red[1][myq][0] + red[1][myq][1] + red[1][myq][2] + red[1][myq][3];
  const float inv = 1.0f / Z;
  half4_t h;
  h[0] = (_Float16)(s0 * inv);
  h[1] = (_Float16)(s1 * inv);
  h[2] = (_Float16)(s2 * inv);
  h[3] = (_Float16)(s3 * inv);
  *(half4_t*)(attn_h + (size_t)(b * NQ + q0 + myq) * NK + kbase) = h;
}

// ---------------------------------------------------------------------------
// Kernel 4: PV via MFMA fp16, k-split by 4 (grid 1024, 4 blocks/CU).
// Partials atomicAdd'ed into out (zeroed by prep_kernel).
// ---------------------------------------------------------------------------
__global__ __launch_bounds__(256) void pv_mfma_kernel(
    const _Float16* __restrict__ attn_h, const _Float16* __restrict__ vT,
    float* __restrict__ out) {
  const int bid = blockIdx.x;
  const int kc  = bid & 3;
  const int nt8 = (bid >> 2) & 7;
  const int mt  = (bid >> 5) & 7;
  const int b   = bid >> 8;
  const int w = threadIdx.x >> 6;
  const int l = threadIdx.x & 63;
  const int mtile = w & 1;
  const int ntile0 = (w >> 1) * 2;
  const int q_lo = mt * 32 + mtile * 16;
  const int d_lo = nt8 * 64 + ntile0 * 16;
  const int k0 = kc * 256;

  const _Float16* arow =
      attn_h + ((size_t)(b * NQ + q_lo + (l & 15))) * NK + k0 + (l >> 4) * 8;
  const _Float16* brow0 =
      vT + ((size_t)(b * ND + d_lo + (l & 15))) * NK + k0 + (l >> 4) * 8;
  const _Float16* brow1 = brow0 + 16 * NK;

  f32x4_t acc0 = {0.f, 0.f, 0.f, 0.f};
  f32x4_t acc1 = {0.f, 0.f, 0.f, 0.f};
  #pragma unroll
  for (int ks = 0; ks < 256; ks += 32) {
    const half8_t a  = *(const half8_t*)(arow + ks);
    const half8_t b0 = *(const half8_t*)(brow0 + ks);
    const half8_t b1 = *(const half8_t*)(brow1 + ks);
    acc0 = __builtin_amdgcn_mfma_f32_16x16x32_f16(a, b0, acc0, 0, 0, 0);
    acc1 = __builtin_amdgcn_mfma_f32_16x16x32_f16(a, b1, acc1, 0, 0, 0);
  }
  const int mrow = q_lo + (l >> 4) * 4;
  const int dcol = d_lo + (l & 15);
  #pragma unroll
  for (int r = 0; r < 4; ++r) {
    atomicAdd(&out[(size_t)(b * NQ + mrow + r) * ND + dcol], acc0[r]);
    atomicAdd(&out[(size_t)(b * NQ + mrow + r) * ND + dcol + 16], acc1[r]);
  }
}

// ---------------------------------------------------------------------------
extern "C" void kernel_launch(void* const* d_in, const int* in_sizes, int n_in,
                              void* d_out, int out_size, void* d_ws, size_t ws_size,
                              hipStream_t stream) {
  const float* queries = (const float*)d_in[0];
  const float* keys    = (const float*)d_in[1];
  const float* values  = (const float*)d_in[2];
  const float* Wq      = (const float*)d_in[3];
  const float* Wk      = (const float*)d_in[4];
  const float* wv      = (const float*)d_in[5];
  const int*   vlen    = (const int*)d_in[6];
  float* out = (float*)d_out;

  // ws layout (bytes, no overlays; total ~8.96 MB; d_ws is ~256 MB):
  char* ws = (char*)d_ws;
  float*     EQ     = (float*)(ws);                    // 512 KB (row-major)
  float*     EKT    = (float*)(ws + (512 << 10));      // 2 MB   (transposed)
  _Float16*  attn_h = (_Float16*)(ws + (2560 << 10));  // 2 MB
  _Float16*  vT     = (_Float16*)(ws + (4608 << 10));  // 4 MB
  _Float16*  WQT    = (_Float16*)(ws + (8704 << 10));  // 128 KB
  _Float16*  WKT    = (_Float16*)(ws + (8832 << 10));  // 128 KB

  prep_kernel<<<528, 256, 0, stream>>>(Wq, Wk, values, WQT, WKT, vT,
                                       (float4*)out);
  proj_mfma_kernel<<<(NB * NQ + NB * NK) / 16, 256, 0, stream>>>(
      queries, keys, WQT, WKT, EQ, EKT);
  scores_softmax_kernel<<<NB * (NQ / 2), 512, 0, stream>>>(EQ, EKT, wv, vlen,
                                                           attn_h);
  pv_mfma_kernel<<<NB * 8 * 8 * 4, 256, 0, stream>>>(attn_h, vT, out);
}

// Round 11
// 58.399 us; speedup vs baseline: 1.8209x; 1.0143x over previous
//
#include <hip/hip_runtime.h>

#define NB 4
#define NQ 256
#define NK 1024
#define ND 512
#define NH 128

typedef _Float16 half8_t __attribute__((ext_vector_type(8)));
typedef _Float16 half4_t __attribute__((ext_vector_type(4)));
typedef _Float16 half2_t __attribute__((ext_vector_type(2)));
typedef float f32x4_t __attribute__((ext_vector_type(4)));

#define TANH_C 2.8853900817779268f  // 2*log2(e): tanh(x)=1-2/(exp2(C*x)+1)

// ---------------------------------------------------------------------------
// Kernel 1 (prep): blocks 0..15  : W (512,128) fp32 -> WT (128,512) fp16
//                  blocks 16..527: values (B,K,D) fp32 -> vT (B,D,K) fp16.
// (No out-zeroing anymore: pv writes every element exactly once now.)
// ---------------------------------------------------------------------------
__global__ __launch_bounds__(256) void prep_kernel(
    const float* __restrict__ Wq, const float* __restrict__ Wk,
    const float* __restrict__ values, _Float16* __restrict__ WQT,
    _Float16* __restrict__ WKT, _Float16* __restrict__ vT) {
  __shared__ float smem[64 * 130];
  const int bid = blockIdx.x;
  const int t = threadIdx.x;

  if (bid < 16) {  // ---- weight transpose: 64-d chunk of Wq or Wk ----
    float(*tile)[129] = (float(*)[129])smem;
    const float* W = (bid >= 8) ? Wk : Wq;
    _Float16* WT = (bid >= 8) ? WKT : WQT;
    const int d0 = (bid & 7) * 64;
    #pragma unroll
    for (int j = 0; j < 32; ++j) {
      const int idx = t + j * 256;
      tile[idx >> 7][idx & 127] = W[(size_t)(d0 + (idx >> 7)) * NH + (idx & 127)];
    }
    __syncthreads();
    #pragma unroll
    for (int j = 0; j < 32; ++j) {
      const int idx = t + j * 256;
      const int h = idx >> 6, r = idx & 63;
      WT[(size_t)h * ND + d0 + r] = (_Float16)tile[r][h];
    }
    return;
  }

  // ---- values transpose (64x64 tile) ----
  const int vb = bid - 16;  // 0..511
  float(*tile)[65] = (float(*)[65])smem;
  const int dt = vb & 7;
  const int kt = (vb >> 3) & 15;
  const int b = vb >> 7;
  const int k0 = kt * 64, d0 = dt * 64;
  {
    const int kl = t >> 4, dl4 = (t & 15) * 4;
    #pragma unroll
    for (int i = 0; i < 4; ++i) {
      const float4 v = *(const float4*)(
          values + ((size_t)(b * NK + k0 + kl + i * 16)) * ND + d0 + dl4);
      tile[dl4 + 0][kl + i * 16] = v.x;
      tile[dl4 + 1][kl + i * 16] = v.y;
      tile[dl4 + 2][kl + i * 16] = v.z;
      tile[dl4 + 3][kl + i * 16] = v.w;
    }
  }
  __syncthreads();
  const int dr = t >> 2, kc = (t & 3) * 16;
  half8_t h0, h1;
  #pragma unroll
  for (int ii = 0; ii < 8; ++ii) {
    h0[ii] = (_Float16)tile[dr][kc + ii];
    h1[ii] = (_Float16)tile[dr][kc + 8 + ii];
  }
  _Float16* dst = vT + ((size_t)(b * ND + d0 + dr)) * NK + k0 + kc;
  *(half8_t*)dst = h0;
  *(half8_t*)(dst + 8) = h1;
}

// ---------------------------------------------------------------------------
// Kernel 2: projection via MFMA fp16 + exp2 epilogue.
// Rows 0..1023 = queries -> EQ[row][h]; rows 1024..5119 = keys ->
// EKT[b][h][k] (transposed, k contiguous; D-fragment rows = 4 consecutive k
// -> single float4 store per fragment).
// ---------------------------------------------------------------------------
__global__ __launch_bounds__(256) void proj_mfma_kernel(
    const float* __restrict__ queries, const float* __restrict__ keys,
    const _Float16* __restrict__ WQT, const _Float16* __restrict__ WKT,
    float* __restrict__ EQ, float* __restrict__ EKT) {
  const int bid = blockIdx.x;
  const int row0 = bid * 16;
  const bool is_q = row0 < NB * NQ;
  const float* X = is_q ? queries : (keys - (size_t)NB * NQ * ND);
  const _Float16* WT = is_q ? WQT : WKT;

  const int w = threadIdx.x >> 6;
  const int l = threadIdx.x & 63;
  const int h0 = w * 32;

  const float* xrow = X + (size_t)(row0 + (l & 15)) * ND + (l >> 4) * 8;
  const _Float16* wt0 = WT + (size_t)(h0 + (l & 15)) * ND + (l >> 4) * 8;
  const _Float16* wt1 = wt0 + 16 * ND;

  f32x4_t acc0 = {0.f, 0.f, 0.f, 0.f};
  f32x4_t acc1 = {0.f, 0.f, 0.f, 0.f};
  #pragma unroll 4
  for (int d = 0; d < ND; d += 32) {
    const float4 x0 = *(const float4*)(xrow + d);
    const float4 x1 = *(const float4*)(xrow + d + 4);
    half8_t a;
    a[0] = (_Float16)x0.x; a[1] = (_Float16)x0.y;
    a[2] = (_Float16)x0.z; a[3] = (_Float16)x0.w;
    a[4] = (_Float16)x1.x; a[5] = (_Float16)x1.y;
    a[6] = (_Float16)x1.z; a[7] = (_Float16)x1.w;
    const half8_t b0 = *(const half8_t*)(wt0 + d);
    const half8_t b1 = *(const half8_t*)(wt1 + d);
    acc0 = __builtin_amdgcn_mfma_f32_16x16x32_f16(a, b0, acc0, 0, 0, 0);
    acc1 = __builtin_amdgcn_mfma_f32_16x16x32_f16(a, b1, acc1, 0, 0, 0);
  }
  const int mrow = row0 + (l >> 4) * 4;
  const int hcol = h0 + (l & 15);
  if (is_q) {
    #pragma unroll
    for (int r = 0; r < 4; ++r) {
      EQ[(size_t)(mrow + r) * NH + hcol] = __builtin_exp2f(TANH_C * acc0[r]);
      EQ[(size_t)(mrow + r) * NH + hcol + 16] = __builtin_exp2f(TANH_C * acc1[r]);
    }
  } else {
    const int rowk = mrow - NB * NQ;  // 0..4095
    const int bb = rowk >> 10;
    const int kk = rowk & 1023;       // multiple of 4 -> 16B aligned
    float4 v0, v1;
    v0.x = __builtin_exp2f(TANH_C * acc0[0]);
    v0.y = __builtin_exp2f(TANH_C * acc0[1]);
    v0.z = __builtin_exp2f(TANH_C * acc0[2]);
    v0.w = __builtin_exp2f(TANH_C * acc0[3]);
    v1.x = __builtin_exp2f(TANH_C * acc1[0]);
    v1.y = __builtin_exp2f(TANH_C * acc1[1]);
    v1.z = __builtin_exp2f(TANH_C * acc1[2]);
    v1.w = __builtin_exp2f(TANH_C * acc1[3]);
    *(float4*)(EKT + ((size_t)(bb * NH + hcol)) * NK + kk) = v0;
    *(float4*)(EKT + ((size_t)(bb * NH + hcol + 16)) * NK + kk) = v1;
  }
}

// ---------------------------------------------------------------------------
// Kernel 3: fused scores + softmax -> fp16 attn, no LDS staging.
// Grid 512 = (b, q-pair); block 512 thr = 8 waves; wave = 128-k chunk,
// covering BOTH q rows (halves EKT traffic vs R10: each EKT element now
// read once per block, 256 MB total). Lane owns 2 adjacent k (float2 loads,
// fully coalesced). 4 waves/SIMD. Paired rcp across h pairs. Masked -> 0
// kept in softmax (ref semantics). Cross-wave softmax via 8-slot LDS reduce.
// ---------------------------------------------------------------------------
__global__ __launch_bounds__(512, 4) void scores_softmax_kernel(
    const float* __restrict__ EQ, const float* __restrict__ EKT,
    const float* __restrict__ wv, const int* __restrict__ vlen,
    _Float16* __restrict__ attn_h) {
  __shared__ float4 eqwv2[2][64];  // [q][h/2] = {eq_h, wv_h, eq_h+1, wv_h+1}
  __shared__ float red[2][2][8];   // [pass][q][wave]
  const int bid = blockIdx.x;      // b*128 + qpair
  const int b = bid >> 7;
  const int q0 = (bid & 127) * 2;
  const int t = threadIdx.x;
  const int w = t >> 6;            // 0..7 = 128-k chunk
  const int l = t & 63;
  const int vl = vlen[b];

  if (t < 128) {
    const int qq = t >> 6, i = t & 63;
    const float* eqrow = EQ + (size_t)(b * NQ + q0 + qq) * NH;
    eqwv2[qq][i] = make_float4(eqrow[2 * i], wv[2 * i],
                               eqrow[2 * i + 1], wv[2 * i + 1]);
  }
  __syncthreads();

  // Wsum = sum_h wv[h]
  float Wsum;
  {
    const float4 a = eqwv2[0][l];
    Wsum = a.y + a.w;
    #pragma unroll
    for (int off = 32; off; off >>= 1) Wsum += __shfl_xor(Wsum, off);
  }

  const int k0 = w * 128;
  float a00 = 0.f, a01 = 0.f, a10 = 0.f, a11 = 0.f;  // [q][k]
  if (k0 < vl) {  // wave-uniform skip of fully-masked chunks
    const float* ekb = EKT + (size_t)(b * NH) * NK + k0 + l * 2;
    #pragma unroll 4
    for (int hh = 0; hh < 64; ++hh) {
      const float4 qw0 = eqwv2[0][hh];  // {eqA, wvA, eqB, wvB} for q0
      const float4 qw1 = eqwv2[1][hh];  // ... for q1
      const float2 ea = *(const float2*)(ekb + (size_t)(2 * hh) * NK);
      const float2 eb = *(const float2*)(ekb + (size_t)(2 * hh + 1) * NK);
      {
        const float da = fmaf(qw0.x, ea.x, 1.f), db = fmaf(qw0.z, eb.x, 1.f);
        a00 = fmaf(fmaf(qw0.y, db, qw0.w * da),
                   __builtin_amdgcn_rcpf(da * db), a00);
      }
      {
        const float da = fmaf(qw0.x, ea.y, 1.f), db = fmaf(qw0.z, eb.y, 1.f);
        a01 = fmaf(fmaf(qw0.y, db, qw0.w * da),
                   __builtin_amdgcn_rcpf(da * db), a01);
      }
      {
        const float da = fmaf(qw1.x, ea.x, 1.f), db = fmaf(qw1.z, eb.x, 1.f);
        a10 = fmaf(fmaf(qw1.y, db, qw1.w * da),
                   __builtin_amdgcn_rcpf(da * db), a10);
      }
      {
        const float da = fmaf(qw1.x, ea.y, 1.f), db = fmaf(qw1.z, eb.y, 1.f);
        a11 = fmaf(fmaf(qw1.y, db, qw1.w * da),
                   __builtin_amdgcn_rcpf(da * db), a11);
      }
    }
  }

  // finalize scores (masked -> 0, reference semantics)
  const int kA = k0 + l * 2, kB = kA + 1;
  float s00 = (kA < vl) ? (Wsum - 2.f * a00) : 0.f;
  float s01 = (kB < vl) ? (Wsum - 2.f * a01) : 0.f;
  float s10 = (kA < vl) ? (Wsum - 2.f * a10) : 0.f;
  float s11 = (kB < vl) ? (Wsum - 2.f * a11) : 0.f;

  // softmax: per-wave reduce, then 8-wave LDS combine (both q rows)
  float m0 = fmaxf(s00, s01), m1 = fmaxf(s10, s11);
  #pragma unroll
  for (int off = 32; off; off >>= 1) {
    m0 = fmaxf(m0, __shfl_xor(m0, off));
    m1 = fmaxf(m1, __shfl_xor(m1, off));
  }
  if (l == 0) { red[0][0][w] = m0; red[0][1][w] = m1; }
  __syncthreads();
  m0 = red[0][0][0]; m1 = red[0][1][0];
  #pragma unroll
  for (int i = 1; i < 8; ++i) {
    m0 = fmaxf(m0, red[0][0][i]);
    m1 = fmaxf(m1, red[0][1][i]);
  }
  const float ce = 1.4426950408889634f;
  s00 = __builtin_exp2f(ce * (s00 - m0));
  s01 = __builtin_exp2f(ce * (s01 - m0));
  s10 = __builtin_exp2f(ce * (s10 - m1));
  s11 = __builtin_exp2f(ce * (s11 - m1));
  float sum0 = s00 + s01, sum1 = s10 + s11;
  #pragma unroll
  for (int off = 32; off; off >>= 1) {
    sum0 += __shfl_xor(sum0, off);
    sum1 += __shfl_xor(sum1, off);
  }
  if (l == 0) { red[1][0][w] = sum0; red[1][1][w] = sum1; }
  __syncthreads();
  float Z0 = 0.f, Z1 = 0.f;
  #pragma unroll
  for (int i = 0; i < 8; ++i) { Z0 += red[1][0][i]; Z1 += red[1][1][i]; }
  const float inv0 = 1.0f / Z0, inv1 = 1.0f / Z1;
  half2_t h0, h1;
  h0[0] = (_Float16)(s00 * inv0); h0[1] = (_Float16)(s01 * inv0);
  h1[0] = (_Float16)(s10 * inv1); h1[1] = (_Float16)(s11 * inv1);
  *(half2_t*)(attn_h + (size_t)(b * NQ + q0) * NK + kA) = h0;
  *(half2_t*)(attn_h + (size_t)(b * NQ + q0 + 1) * NK + kA) = h1;
}

// ---------------------------------------------------------------------------
// Kernel 4: PV via MFMA fp16, full-K per block, NO atomics.
// Grid 512 = (b, 16-q tile, 64-d tile); 2 blocks/CU. Wave = one 16-d
// n-fragment; 32 k-steps of 32. Plain float stores (each out elem written
// exactly once) -- removes atomic contention AND the out-zeroing pass.
// ---------------------------------------------------------------------------
__global__ __launch_bounds__(256) void pv_mfma_kernel(
    const _Float16* __restrict__ attn_h, const _Float16* __restrict__ vT,
    float* __restrict__ out) {
  const int bid = blockIdx.x;
  const int dt = bid & 7;           // 64-d tile
  const int qt = (bid >> 3) & 15;   // 16-q tile
  const int b  = bid >> 7;
  const int w = threadIdx.x >> 6;   // wave = 16-d sub-tile
  const int l = threadIdx.x & 63;
  const int q_lo = qt * 16;
  const int d_lo = dt * 64 + w * 16;

  const _Float16* arow =
      attn_h + ((size_t)(b * NQ + q_lo + (l & 15))) * NK + (l >> 4) * 8;
  const _Float16* brow =
      vT + ((size_t)(b * ND + d_lo + (l & 15))) * NK + (l >> 4) * 8;

  f32x4_t acc = {0.f, 0.f, 0.f, 0.f};
  #pragma unroll 8
  for (int ks = 0; ks < NK; ks += 32) {
    const half8_t a = *(const half8_t*)(arow + ks);
    const half8_t bb = *(const half8_t*)(brow + ks);
    acc = __builtin_amdgcn_mfma_f32_16x16x32_f16(a, bb, acc, 0, 0, 0);
  }
  const int mrow = q_lo + (l >> 4) * 4;
  const int dcol = d_lo + (l & 15);
  #pragma unroll
  for (int r = 0; r < 4; ++r)
    out[(size_t)(b * NQ + mrow + r) * ND + dcol] = acc[r];
}

// ---------------------------------------------------------------------------
extern "C" void kernel_launch(void* const* d_in, const int* in_sizes, int n_in,
                              void* d_out, int out_size, void* d_ws, size_t ws_size,
                              hipStream_t stream) {
  const float* queries = (const float*)d_in[0];
  const float* keys    = (const float*)d_in[1];
  const float* values  = (const float*)d_in[2];
  const float* Wq      = (const float*)d_in[3];
  const float* Wk      = (const float*)d_in[4];
  const float* wv      = (const float*)d_in[5];
  const int*   vlen    = (const int*)d_in[6];
  float* out = (float*)d_out;

  // ws layout (bytes; total ~8.96 MB; d_ws is ~256 MB):
  char* ws = (char*)d_ws;
  float*     EQ     = (float*)(ws);                    // 512 KB (row-major)
  float*     EKT    = (float*)(ws + (512 << 10));      // 2 MB   (transposed)
  _Float16*  attn_h = (_Float16*)(ws + (2560 << 10));  // 2 MB
  _Float16*  vT     = (_Float16*)(ws + (4608 << 10));  // 4 MB
  _Float16*  WQT    = (_Float16*)(ws + (8704 << 10));  // 128 KB
  _Float16*  WKT    = (_Float16*)(ws + (8832 << 10));  // 128 KB

  prep_kernel<<<528, 256, 0, stream>>>(Wq, Wk, values, WQT, WKT, vT);
  proj_mfma_kernel<<<(NB * NQ + NB * NK) / 16, 256, 0, stream>>>(
      queries, keys, WQT, WKT, EQ, EKT);
  scores_softmax_kernel<<<NB * (NQ / 2), 512, 0, stream>>>(EQ, EKT, wv, vlen,
                                                           attn_h);
  pv_mfma_kernel<<<NB * 16 * 8, 256, 0, stream>>>(attn_h, vT, out);
}

// Round 12
// 54.174 us; speedup vs baseline: 1.9629x; 1.0780x over previous
//
#include <hip/hip_runtime.h>

#define NB 4
#define NQ 256
#define NK 1024
#define ND 512
#define NH 128

typedef _Float16 half8_t __attribute__((ext_vector_type(8)));
typedef _Float16 half4_t __attribute__((ext_vector_type(4)));
typedef _Float16 half2_t __attribute__((ext_vector_type(2)));
typedef float f32x4_t __attribute__((ext_vector_type(4)));

#define TANH_C 2.8853900817779268f  // 2*log2(e): tanh(x)=1-2/(exp2(C*x)+1)

// ---------------------------------------------------------------------------
// Kernel 1 (proj + vT, fused; independent roles per block):
//  blocks 0..319 : projection via MFMA fp16 with INLINE W->LDS transpose.
//    Block = 64 rows x 32 h (wave w = rows row0+w*16). W-slice (512d x 32h)
//    staged once into LDS fp16 [32][520], XOR-swizzled (d ^ ((h&7)<<3)) so
//    ds_read_b128 B-frags are ~2-way (free). Kills the separate WT kernel
//    AND replaces ~200cyc L2 B-loads with ~12cyc LDS reads (latency fix for
//    the 1.25-block/CU occupancy regime).
//    Rows 0..1023 -> EQ[row][h]; rows 1024..5119 -> EKT[b][h][k] (float4
//    store along k, same as R11).
//  blocks 320..831: values (B,K,D) fp32 -> vT (B,D,K) fp16 (R11 prep body).
// ---------------------------------------------------------------------------
__global__ __launch_bounds__(256) void projvt_kernel(
    const float* __restrict__ queries, const float* __restrict__ keys,
    const float* __restrict__ Wq, const float* __restrict__ Wk,
    const float* __restrict__ values, float* __restrict__ EQ,
    float* __restrict__ EKT, _Float16* __restrict__ vT) {
  __shared__ __align__(16) char smem[33280];
  const int bid = blockIdx.x;
  const int t = threadIdx.x;

  if (bid < 320) {  // ---------------- projection ----------------
    _Float16* wlds = (_Float16*)smem;  // [32][520] halfs, swizzled
    const int hgrp = bid & 3;
    const int rblk = bid >> 2;         // 0..79
    const int row0_blk = rblk * 64;
    const bool is_q = row0_blk < NB * NQ;
    const float* X = is_q ? queries : (keys - (size_t)NB * NQ * ND);
    const float* W = is_q ? Wq : Wk;
    const int h0 = hgrp * 32;

    {  // stage W[*][h0..h0+32) -> wlds[j][d ^ ((j&7)<<3)]
      const int j = t & 31;
      const int dg = t >> 5;  // 0..7
      const int jx = (j & 7) << 3;
      #pragma unroll 8
      for (int pass = 0; pass < 64; ++pass) {
        const int d = pass * 8 + dg;
        wlds[j * 520 + (d ^ jx)] = (_Float16)W[(size_t)d * NH + h0 + j];
      }
    }
    __syncthreads();

    const int w = t >> 6;
    const int l = t & 63;
    const int row0 = row0_blk + w * 16;
    const float* xrow = X + (size_t)(row0 + (l & 15)) * ND + (l >> 4) * 8;
    const int hA = l & 15;
    const int xorA = (hA & 7) << 3;  // same for rows hA and hA+16

    f32x4_t acc0 = {0.f, 0.f, 0.f, 0.f};
    f32x4_t acc1 = {0.f, 0.f, 0.f, 0.f};
    #pragma unroll 4
    for (int d = 0; d < ND; d += 32) {
      const float4 x0 = *(const float4*)(xrow + d);
      const float4 x1 = *(const float4*)(xrow + d + 4);
      half8_t a;
      a[0] = (_Float16)x0.x; a[1] = (_Float16)x0.y;
      a[2] = (_Float16)x0.z; a[3] = (_Float16)x0.w;
      a[4] = (_Float16)x1.x; a[5] = (_Float16)x1.y;
      a[6] = (_Float16)x1.z; a[7] = (_Float16)x1.w;
      const int dfrag = d + (l >> 4) * 8;
      const half8_t b0 =
          *(const half8_t*)&wlds[hA * 520 + (dfrag ^ xorA)];
      const half8_t b1 =
          *(const half8_t*)&wlds[(16 + hA) * 520 + (dfrag ^ xorA)];
      acc0 = __builtin_amdgcn_mfma_f32_16x16x32_f16(a, b0, acc0, 0, 0, 0);
      acc1 = __builtin_amdgcn_mfma_f32_16x16x32_f16(a, b1, acc1, 0, 0, 0);
    }
    const int mrow = row0 + (l >> 4) * 4;
    const int hcol = h0 + hA;
    if (is_q) {
      #pragma unroll
      for (int r = 0; r < 4; ++r) {
        EQ[(size_t)(mrow + r) * NH + hcol] = __builtin_exp2f(TANH_C * acc0[r]);
        EQ[(size_t)(mrow + r) * NH + hcol + 16] =
            __builtin_exp2f(TANH_C * acc1[r]);
      }
    } else {
      const int rowk = mrow - NB * NQ;  // 0..4095
      const int bb = rowk >> 10;
      const int kk = rowk & 1023;       // multiple of 4 -> 16B aligned
      float4 v0, v1;
      v0.x = __builtin_exp2f(TANH_C * acc0[0]);
      v0.y = __builtin_exp2f(TANH_C * acc0[1]);
      v0.z = __builtin_exp2f(TANH_C * acc0[2]);
      v0.w = __builtin_exp2f(TANH_C * acc0[3]);
      v1.x = __builtin_exp2f(TANH_C * acc1[0]);
      v1.y = __builtin_exp2f(TANH_C * acc1[1]);
      v1.z = __builtin_exp2f(TANH_C * acc1[2]);
      v1.w = __builtin_exp2f(TANH_C * acc1[3]);
      *(float4*)(EKT + ((size_t)(bb * NH + hcol)) * NK + kk) = v0;
      *(float4*)(EKT + ((size_t)(bb * NH + hcol + 16)) * NK + kk) = v1;
    }
    return;
  }

  // ---------------- values transpose (64x64 tile) ----------------
  const int vb = bid - 320;  // 0..511
  float(*tile)[65] = (float(*)[65])smem;  // 16640 B
  const int dt = vb & 7;
  const int kt = (vb >> 3) & 15;
  const int b = vb >> 7;
  const int k0 = kt * 64, d0 = dt * 64;
  {
    const int kl = t >> 4, dl4 = (t & 15) * 4;
    #pragma unroll
    for (int i = 0; i < 4; ++i) {
      const float4 v = *(const float4*)(
          values + ((size_t)(b * NK + k0 + kl + i * 16)) * ND + d0 + dl4);
      tile[dl4 + 0][kl + i * 16] = v.x;
      tile[dl4 + 1][kl + i * 16] = v.y;
      tile[dl4 + 2][kl + i * 16] = v.z;
      tile[dl4 + 3][kl + i * 16] = v.w;
    }
  }
  __syncthreads();
  const int dr = t >> 2, kc = (t & 3) * 16;
  half8_t h0v, h1v;
  #pragma unroll
  for (int ii = 0; ii < 8; ++ii) {
    h0v[ii] = (_Float16)tile[dr][kc + ii];
    h1v[ii] = (_Float16)tile[dr][kc + 8 + ii];
  }
  _Float16* dst = vT + ((size_t)(b * ND + d0 + dr)) * NK + k0 + kc;
  *(half8_t*)dst = h0v;
  *(half8_t*)(dst + 8) = h1v;
}

// ---------------------------------------------------------------------------
// Kernel 2: fused scores + softmax -> fp16 attn (R11, unchanged).
// Grid 512 = (b, q-pair); 8 waves; wave = 128-k chunk covering both q rows.
// ---------------------------------------------------------------------------
__global__ __launch_bounds__(512, 4) void scores_softmax_kernel(
    const float* __restrict__ EQ, const float* __restrict__ EKT,
    const float* __restrict__ wv, const int* __restrict__ vlen,
    _Float16* __restrict__ attn_h) {
  __shared__ float4 eqwv2[2][64];
  __shared__ float red[2][2][8];
  const int bid = blockIdx.x;
  const int b = bid >> 7;
  const int q0 = (bid & 127) * 2;
  const int t = threadIdx.x;
  const int w = t >> 6;
  const int l = t & 63;
  const int vl = vlen[b];

  if (t < 128) {
    const int qq = t >> 6, i = t & 63;
    const float* eqrow = EQ + (size_t)(b * NQ + q0 + qq) * NH;
    eqwv2[qq][i] = make_float4(eqrow[2 * i], wv[2 * i],
                               eqrow[2 * i + 1], wv[2 * i + 1]);
  }
  __syncthreads();

  float Wsum;
  {
    const float4 a = eqwv2[0][l];
    Wsum = a.y + a.w;
    #pragma unroll
    for (int off = 32; off; off >>= 1) Wsum += __shfl_xor(Wsum, off);
  }

  const int k0 = w * 128;
  float a00 = 0.f, a01 = 0.f, a10 = 0.f, a11 = 0.f;
  if (k0 < vl) {
    const float* ekb = EKT + (size_t)(b * NH) * NK + k0 + l * 2;
    #pragma unroll 4
    for (int hh = 0; hh < 64; ++hh) {
      const float4 qw0 = eqwv2[0][hh];
      const float4 qw1 = eqwv2[1][hh];
      const float2 ea = *(const float2*)(ekb + (size_t)(2 * hh) * NK);
      const float2 eb = *(const float2*)(ekb + (size_t)(2 * hh + 1) * NK);
      {
        const float da = fmaf(qw0.x, ea.x, 1.f), db = fmaf(qw0.z, eb.x, 1.f);
        a00 = fmaf(fmaf(qw0.y, db, qw0.w * da),
                   __builtin_amdgcn_rcpf(da * db), a00);
      }
      {
        const float da = fmaf(qw0.x, ea.y, 1.f), db = fmaf(qw0.z, eb.y, 1.f);
        a01 = fmaf(fmaf(qw0.y, db, qw0.w * da),
                   __builtin_amdgcn_rcpf(da * db), a01);
      }
      {
        const float da = fmaf(qw1.x, ea.x, 1.f), db = fmaf(qw1.z, eb.x, 1.f);
        a10 = fmaf(fmaf(qw1.y, db, qw1.w * da),
                   __builtin_amdgcn_rcpf(da * db), a10);
      }
      {
        const float da = fmaf(qw1.x, ea.y, 1.f), db = fmaf(qw1.z, eb.y, 1.f);
        a11 = fmaf(fmaf(qw1.y, db, qw1.w * da),
                   __builtin_amdgcn_rcpf(da * db), a11);
      }
    }
  }

  const int kA = k0 + l * 2, kB = kA + 1;
  float s00 = (kA < vl) ? (Wsum - 2.f * a00) : 0.f;
  float s01 = (kB < vl) ? (Wsum - 2.f * a01) : 0.f;
  float s10 = (kA < vl) ? (Wsum - 2.f * a10) : 0.f;
  float s11 = (kB < vl) ? (Wsum - 2.f * a11) : 0.f;

  float m0 = fmaxf(s00, s01), m1 = fmaxf(s10, s11);
  #pragma unroll
  for (int off = 32; off; off >>= 1) {
    m0 = fmaxf(m0, __shfl_xor(m0, off));
    m1 = fmaxf(m1, __shfl_xor(m1, off));
  }
  if (l == 0) { red[0][0][w] = m0; red[0][1][w] = m1; }
  __syncthreads();
  m0 = red[0][0][0]; m1 = red[0][1][0];
  #pragma unroll
  for (int i = 1; i < 8; ++i) {
    m0 = fmaxf(m0, red[0][0][i]);
    m1 = fmaxf(m1, red[0][1][i]);
  }
  const float ce = 1.4426950408889634f;
  s00 = __builtin_exp2f(ce * (s00 - m0));
  s01 = __builtin_exp2f(ce * (s01 - m0));
  s10 = __builtin_exp2f(ce * (s10 - m1));
  s11 = __builtin_exp2f(ce * (s11 - m1));
  float sum0 = s00 + s01, sum1 = s10 + s11;
  #pragma unroll
  for (int off = 32; off; off >>= 1) {
    sum0 += __shfl_xor(sum0, off);
    sum1 += __shfl_xor(sum1, off);
  }
  if (l == 0) { red[1][0][w] = sum0; red[1][1][w] = sum1; }
  __syncthreads();
  float Z0 = 0.f, Z1 = 0.f;
  #pragma unroll
  for (int i = 0; i < 8; ++i) { Z0 += red[1][0][i]; Z1 += red[1][1][i]; }
  const float inv0 = 1.0f / Z0, inv1 = 1.0f / Z1;
  half2_t h0, h1;
  h0[0] = (_Float16)(s00 * inv0); h0[1] = (_Float16)(s01 * inv0);
  h1[0] = (_Float16)(s10 * inv1); h1[1] = (_Float16)(s11 * inv1);
  *(half2_t*)(attn_h + (size_t)(b * NQ + q0) * NK + kA) = h0;
  *(half2_t*)(attn_h + (size_t)(b * NQ + q0 + 1) * NK + kA) = h1;
}

// ---------------------------------------------------------------------------
// Kernel 3: PV via MFMA fp16, full-K per block, plain stores (R11, unchanged).
// ---------------------------------------------------------------------------
__global__ __launch_bounds__(256) void pv_mfma_kernel(
    const _Float16* __restrict__ attn_h, const _Float16* __restrict__ vT,
    float* __restrict__ out) {
  const int bid = blockIdx.x;
  const int dt = bid & 7;
  const int qt = (bid >> 3) & 15;
  const int b  = bid >> 7;
  const int w = threadIdx.x >> 6;
  const int l = threadIdx.x & 63;
  const int q_lo = qt * 16;
  const int d_lo = dt * 64 + w * 16;

  const _Float16* arow =
      attn_h + ((size_t)(b * NQ + q_lo + (l & 15))) * NK + (l >> 4) * 8;
  const _Float16* brow =
      vT + ((size_t)(b * ND + d_lo + (l & 15))) * NK + (l >> 4) * 8;

  f32x4_t acc = {0.f, 0.f, 0.f, 0.f};
  #pragma unroll 8
  for (int ks = 0; ks < NK; ks += 32) {
    const half8_t a = *(const half8_t*)(arow + ks);
    const half8_t bb = *(const half8_t*)(brow + ks);
    acc = __builtin_amdgcn_mfma_f32_16x16x32_f16(a, bb, acc, 0, 0, 0);
  }
  const int mrow = q_lo + (l >> 4) * 4;
  const int dcol = d_lo + (l & 15);
  #pragma unroll
  for (int r = 0; r < 4; ++r)
    out[(size_t)(b * NQ + mrow + r) * ND + dcol] = acc[r];
}

// ---------------------------------------------------------------------------
extern "C" void kernel_launch(void* const* d_in, const int* in_sizes, int n_in,
                              void* d_out, int out_size, void* d_ws, size_t ws_size,
                              hipStream_t stream) {
  const float* queries = (const float*)d_in[0];
  const float* keys    = (const float*)d_in[1];
  const float* values  = (const float*)d_in[2];
  const float* Wq      = (const float*)d_in[3];
  const float* Wk      = (const float*)d_in[4];
  const float* wv      = (const float*)d_in[5];
  const int*   vlen    = (const int*)d_in[6];
  float* out = (float*)d_out;

  // ws layout (bytes; total ~8.6 MB; d_ws is ~256 MB):
  char* ws = (char*)d_ws;
  float*     EQ     = (float*)(ws);                    // 512 KB (row-major)
  float*     EKT    = (float*)(ws + (512 << 10));      // 2 MB   (transposed)
  _Float16*  attn_h = (_Float16*)(ws + (2560 << 10));  // 2 MB
  _Float16*  vT     = (_Float16*)(ws + (4608 << 10));  // 4 MB

  projvt_kernel<<<832, 256, 0, stream>>>(queries, keys, Wq, Wk, values,
                                         EQ, EKT, vT);
  scores_softmax_kernel<<<NB * (NQ / 2), 512, 0, stream>>>(EQ, EKT, wv, vlen,
                                                           attn_h);
  pv_mfma_kernel<<<NB * 16 * 8, 256, 0, stream>>>(attn_h, vT, out);
}